// Round 7
// baseline (148.074 us; speedup 1.0000x reference)
//
#include <hip/hip_runtime.h>

// Problem constants
#define T_LEN 4096
#define N_WIN 3969          // T - L + 1
#define K_SH  128
#define L_SH  128
#define B_SZ  256

#define SSTR  136           // S row stride (bf16 elems), 272 B  (fallback kernel)
#define XSTR  4360          // fallback x copy stride (bf16 elems)

// Eighth-split kernel: x copy stride (bf16 elems). 648*2 = 1296 B; dwords 324
// ≡ 4 (mod 32) -> 8 copy bases on distinct bank quads (same property as XSTR).
// Covers 512 windows + 127 lag + pad; max tile read 1264 B <= 1296 B.
#define XSTR_E 648
#define W_EIGHTH 512

typedef __attribute__((ext_vector_type(8))) __bf16 bf16x8;
typedef __attribute__((ext_vector_type(4))) float f32x4;
typedef _Float16 h2 __attribute__((ext_vector_type(2)));   // packed half pair

__device__ __forceinline__ unsigned short f2bf(float f) {
    union { float f; unsigned int u; } c; c.f = f;
    unsigned int u = c.u + 0x7fff + ((c.u >> 16) & 1u);
    return (unsigned short)(u >> 16);
}
__device__ __forceinline__ unsigned int pack2(unsigned short lo, unsigned short hi) {
    return (unsigned int)lo | ((unsigned int)hi << 16);
}

// ---- packed-f16 selection primitives (each op handles BOTH lists) ----
__device__ __forceinline__ h2 max2(h2 a, h2 b) { return __builtin_elementwise_max(a, b); }
__device__ __forceinline__ h2 min2(h2 a, h2 b) { return __builtin_elementwise_min(a, b); }
__device__ __forceinline__ h2 cvt2(float lo, float hi) {   // lo -> elem0, hi -> elem1
    return __builtin_bit_cast(h2, __builtin_amdgcn_cvt_pkrtz(lo, hi));
}
__device__ __forceinline__ void ce2(h2& hi, h2& lo) {
    const h2 m = max2(hi, lo);
    lo = min2(hi, lo);
    hi = m;
}
__device__ __forceinline__ void sort4_2(h2& a, h2& b, h2& c, h2& d) {
    ce2(a, b); ce2(c, d); ce2(a, c); ce2(b, d); ce2(b, c);
}
__device__ __forceinline__ void merge44_top5_2(h2 a0, h2 a1, h2 a2, h2 a3,
                                               h2 b0, h2 b1, h2 b2, h2 b3,
                                               h2& r0, h2& r1, h2& r2, h2& r3, h2& r4) {
    ce2(a0, b0); ce2(a2, b2); ce2(b0, a2);
    ce2(a1, b1); ce2(a3, b3); ce2(b1, a3);
    r0 = a0;
    r1 = a1; r2 = b0; ce2(r1, r2);
    r3 = b1; r4 = a2; ce2(r3, r4);
}
__device__ __forceinline__ void merge55_2(h2& r0, h2& r1, h2& r2, h2& r3, h2& r4,
                                          h2 s0, h2 s1, h2 s2, h2 s3, h2 s4) {
    const h2 m00 = min2(r0, s0);
    const h2 m10 = min2(r1, s0), m01 = min2(r0, s1);
    const h2 m20 = min2(r2, s0), m11 = min2(r1, s1), m02 = min2(r0, s2);
    const h2 m30 = min2(r3, s0), m21 = min2(r2, s1), m12 = min2(r1, s2), m03 = min2(r0, s3);
    const h2 n0 = max2(r0, s0);
    const h2 n1 = max2(max2(r1, s1), m00);
    const h2 n2 = max2(max2(r2, s2), max2(m10, m01));
    const h2 n3 = max2(max2(max2(r3, s3), m20), max2(m11, m02));
    const h2 n4 = max2(max2(max2(r4, s4), max2(m30, m03)), max2(m21, m12));
    r0 = n0; r1 = n1; r2 = n2; r3 = n3; r4 = n4;
}
__device__ __forceinline__ void insert1_2(h2 v, h2* rt) {
    h2 b = max2(rt[4], v); h2 m;
    m = max2(rt[3], b);     b     = min2(rt[3], b);     rt[3] = m;
    m = max2(rt[2], rt[3]); rt[3] = min2(rt[2], rt[3]); rt[2] = m;
    m = max2(rt[1], rt[2]); rt[2] = min2(rt[1], rt[2]); rt[1] = m;
    m = max2(rt[0], rt[1]); rt[1] = min2(rt[0], rt[1]); rt[0] = m;
    rt[4] = b;
}
__device__ __forceinline__ void select32(const f32x4* acc0, const f32x4* acc1, h2* rt) {
    h2 p[16];
    #pragma unroll
    for (int m = 0; m < 4; ++m)
        #pragma unroll
        for (int i = 0; i < 4; ++i)
            p[4 * m + i] = cvt2(acc0[m][i], acc1[m][i]);
    sort4_2(p[0], p[1], p[2],  p[3]);
    sort4_2(p[4], p[5], p[6],  p[7]);
    sort4_2(p[8], p[9], p[10], p[11]);
    sort4_2(p[12], p[13], p[14], p[15]);
    h2 u0, u1, u2, u3, u4, v0, v1, v2, v3, v4;
    merge44_top5_2(p[0], p[1], p[2],  p[3],  p[4],  p[5],  p[6],  p[7],  u0, u1, u2, u3, u4);
    merge44_top5_2(p[8], p[9], p[10], p[11], p[12], p[13], p[14], p[15], v0, v1, v2, v3, v4);
    merge55_2(u0, u1, u2, u3, u4, v0, v1, v2, v3, v4);
    merge55_2(rt[0], rt[1], rt[2], rt[3], rt[4], u0, u1, u2, u3, u4);
}

// ===================== eighth-split kernel (primary path) =====================
// grid = 8*B (2048 blocks), 256 threads (4 waves). Block (b, qt): batch row b,
// windows [512*qt, 512*qt+512) (qt=7: [3584,3968] = 6 steps + boundary 3968).
// Wave w = wp in 0..3 owns shapelet pairs {2wp, 2wp+1}; lane (q,r) packs lists
// for ksA=32wp+r (elem0) and ksB=ksA+16 (elem1). Each wave runs ALL steps of
// the block's window range (64 windows/step).
//
// LDS = 10,880 B (8 x-copies of 648 elems + 128 row-means) -> 8 blocks/CU
// (2048 threads, 87 KB LDS, VGPR<=64 via launch_bounds) = 32 waves/CU.
// No S tile: bfr fragments gathered from global s (L2/L3-resident) minus the
// LDS-computed row means. Inner TILE_STEP identical to the verified R4 loop.
__global__ __launch_bounds__(256, 8)
void shapelet_oct_kernel(const float* __restrict__ x,
                         const float* __restrict__ s,
                         unsigned int* __restrict__ wslists) {
    __shared__ __align__(16) unsigned short ldsX[8 * XSTR_E];   // 10,368 B
    __shared__ float ldsMean[K_SH];                             // 512 B

    const int t    = threadIdx.x;
    const int lane = t & 63;
    const int w    = t >> 6;          // = wp, 0..3
    const int r    = lane & 15;
    const int q    = lane >> 4;
    const int c7   = lane & 7;
    const int ub   = (lane >> 3) & 1;
    const int bid  = blockIdx.x;
    const int b    = bid >> 3;
    const int qt   = bid & 7;
    const int qbase = qt << 9;        // 512*qt

    // ---- S row means: 2 threads per row, 64 floats each ----
    {
        const int row = t >> 1, half = t & 1;
        const float4* sp = (const float4*)(s + row * L_SH + half * 64);
        float sum = 0.0f;
        #pragma unroll
        for (int j = 0; j < 16; ++j) {
            const float4 v = sp[j];
            sum += (v.x + v.y) + (v.z + v.w);
        }
        sum += __shfl_xor(sum, 1);
        if (!half) ldsMean[row] = sum * (1.0f / 128.0f);
    }

    // ---- stage x slice as 8 shifted bf16 copies ----
    {
        const float* __restrict__ xb = x + (size_t)b * T_LEN + qbase;
        const int lim = T_LEN - qbase;       // >= 1024 for qt<=6; 512 for qt=7
        const int a = t & 7;
        for (int i = (t >> 3); i < XSTR_E / 8; i += 32) {    // 81 chunks/copy
            const int p0 = 8 * i;
            float xv[16];
            if (p0 + 16 <= lim) {
                const float4* sp = (const float4*)(xb + p0);
                #pragma unroll
                for (int j = 0; j < 4; ++j) *(float4*)(xv + 4 * j) = sp[j];
            } else {
                #pragma unroll
                for (int j = 0; j < 16; ++j) {
                    const int gi = p0 + j;
                    xv[j] = (gi < lim) ? xb[gi] : 0.0f;
                }
            }
            unsigned short bv[16];
            #pragma unroll
            for (int j = 0; j < 16; ++j) bv[j] = f2bf(xv[j]);
            uint4 o;
            o.x = pack2(bv[a],     bv[a + 1]);
            o.y = pack2(bv[a + 2], bv[a + 3]);
            o.z = pack2(bv[a + 4], bv[a + 5]);
            o.w = pack2(bv[a + 6], bv[a + 7]);
            *(uint4*)((char*)ldsX + a * (XSTR_E * 2) + 2 * p0) = o;
        }
    }
    __syncthreads();

    // ---- bfr fragments directly from global s, centered by LDS means ----
    bf16x8 bfr[2][4];
    #pragma unroll
    for (int kk = 0; kk < 2; ++kk) {
        const int krow = (2 * w + kk) * 16 + r;
        const float mean = ldsMean[krow];
        #pragma unroll
        for (int c = 0; c < 4; ++c) {
            const float4* sp = (const float4*)(s + krow * L_SH + 32 * c + 8 * q);
            const float4 v0 = sp[0], v1 = sp[1];
            uint4 o;
            o.x = pack2(f2bf(v0.x - mean), f2bf(v0.y - mean));
            o.y = pack2(f2bf(v0.z - mean), f2bf(v0.w - mean));
            o.z = pack2(f2bf(v1.x - mean), f2bf(v1.y - mean));
            o.w = pack2(f2bf(v1.z - mean), f2bf(v1.w - mean));
            bfr[kk][c] = __builtin_bit_cast(bf16x8, o);
        }
    }

    // packed running top-5
    h2 rt[5];
    #pragma unroll
    for (int i = 0; i < 5; ++i) rt[i] = __builtin_bit_cast(h2, 0xFC00FC00u);  // (-inf,-inf)

    // 64 windows per step; 128 B per step per copy
    const char* xp = (const char*)ldsX + c7 * (XSTR_E * 2) + 16 * q + 16 * ub;

    const f32x4 ZCC = (f32x4){0.f, 0.f, 0.f, 0.f};

#define TILE_STEP                                                               \
    {                                                                           \
        bf16x8 afr[10];                                                         \
        _Pragma("unroll")                                                       \
        for (int j = 0; j < 10; ++j)                                            \
            afr[j] = __builtin_bit_cast(bf16x8, *(const uint4*)(xp + 32 * j));  \
        xp += 128;                                                              \
        f32x4 acc0[4], acc1[4];                                                 \
        _Pragma("unroll")                                                       \
        for (int m = 0; m < 4; ++m) {                                           \
            acc0[m] = __builtin_amdgcn_mfma_f32_16x16x32_bf16(afr[m], bfr[0][0], ZCC, 0, 0, 0); \
            acc1[m] = __builtin_amdgcn_mfma_f32_16x16x32_bf16(afr[m], bfr[1][0], ZCC, 0, 0, 0); \
        }                                                                       \
        _Pragma("unroll")                                                       \
        for (int c = 1; c < 4; ++c) {                                           \
            _Pragma("unroll")                                                   \
            for (int m = 0; m < 4; ++m) {                                       \
                acc0[m] = __builtin_amdgcn_mfma_f32_16x16x32_bf16(afr[m + 2*c], bfr[0][c], acc0[m], 0, 0, 0); \
                acc1[m] = __builtin_amdgcn_mfma_f32_16x16x32_bf16(afr[m + 2*c], bfr[1][c], acc1[m], 0, 0, 0); \
            }                                                                   \
        }                                                                       \
        select32(acc0, acc1, rt);                                               \
    }

    const int nst = (qt == 7) ? 6 : 8;
    for (int st = 0; st < nst; ++st) { TILE_STEP }
#undef TILE_STEP

    // ---- boundary window n = 3968 (qt=7 only; local window 384) ----
    if (qt == 7) {
        f32x4 e0 = (f32x4){0.f, 0.f, 0.f, 0.f};
        f32x4 e1 = (f32x4){0.f, 0.f, 0.f, 0.f};
        const char* eb = (const char*)ldsX + c7 * (XSTR_E * 2) + 768 + 16 * q + 16 * ub;
        #pragma unroll
        for (int c = 0; c < 4; ++c) {
            const bf16x8 af = __builtin_bit_cast(bf16x8, *(const uint4*)(eb + 64 * c));
            e0 = __builtin_amdgcn_mfma_f32_16x16x32_bf16(af, bfr[0][c], e0, 0, 0, 0);
            e1 = __builtin_amdgcn_mfma_f32_16x16x32_bf16(af, bfr[1][c], e1, 0, 0, 0);
        }
        if (q == 0) insert1_2(cvt2(e0[0], e1[0]), rt);
    }

    // ---- butterfly merge across quads (q bits: lanes 16, 32 apart) ----
    #pragma unroll
    for (int mask = 16; mask <= 32; mask <<= 1) {
        h2 sv[5];
        #pragma unroll
        for (int i = 0; i < 5; ++i)
            sv[i] = __builtin_bit_cast(h2, __shfl_xor(__builtin_bit_cast(int, rt[i]), mask));
        merge55_2(rt[0], rt[1], rt[2], rt[3], rt[4], sv[0], sv[1], sv[2], sv[3], sv[4]);
    }

    // ---- write packed top-5 lists: [b][qt][pair = w*16+r][5] u32 ----
    if (q == 0) {
        unsigned int* p = wslists + ((size_t)(b * 8 + qt) * 64 + (w * 16 + r)) * 5;
        #pragma unroll
        for (int i = 0; i < 5; ++i) p[i] = __builtin_bit_cast(unsigned int, rt[i]);
    }
}

// Merge pass: thread per (b, pair); merges the 8 window-eighth lists, emits
// the 8 output features.
__global__ __launch_bounds__(256)
void shapelet_merge8_kernel(const unsigned int* __restrict__ wslists,
                            float* __restrict__ out) {
    const int j = blockIdx.x * 256 + threadIdx.x;   // 0..16383
    const int b = j >> 6;
    const int pair = j & 63;
    h2 rt[5];
    {
        const unsigned int* p = wslists + ((size_t)(b * 8 + 0) * 64 + pair) * 5;
        #pragma unroll
        for (int i = 0; i < 5; ++i) rt[i] = __builtin_bit_cast(h2, p[i]);
    }
    #pragma unroll
    for (int e = 1; e < 8; ++e) {
        const unsigned int* p = wslists + ((size_t)(b * 8 + e) * 64 + pair) * 5;
        h2 sv[5];
        #pragma unroll
        for (int i = 0; i < 5; ++i) sv[i] = __builtin_bit_cast(h2, p[i]);
        merge55_2(rt[0], rt[1], rt[2], rt[3], rt[4], sv[0], sv[1], sv[2], sv[3], sv[4]);
    }

    const float A0 = (float)rt[0][0], A1 = (float)rt[1][0], A2 = (float)rt[2][0],
                A3 = (float)rt[3][0], A4 = (float)rt[4][0];
    const float B0 = (float)rt[0][1], B1 = (float)rt[1][1], B2 = (float)rt[2][1],
                B3 = (float)rt[3][1], B4 = (float)rt[4][1];
    float* ob = out + (size_t)b * (4 * K_SH);
    const int ksA = 32 * (pair >> 4) + (pair & 15), ksB = ksA + 16;
    const float mA = (((A0 + A1) + (A2 + A3)) + A4) * 0.2f;
    const float mB = (((B0 + B1) + (B2 + B3)) + B4) * 0.2f;
    ob[ksA]           = A0;
    ob[K_SH + ksA]    = mA;
    ob[2*K_SH + ksA]  = A1;
    ob[3*K_SH + ksA]  = fmaxf(A0 - A1, 0.0f);
    ob[ksB]           = B0;
    ob[K_SH + ksB]    = mB;
    ob[2*K_SH + ksB]  = B1;
    ob[3*K_SH + ksB]  = fmaxf(B0 - B1, 0.0f);
}

// ===================== fallback: proven R4 fused kernel (46.4 us) ============
__global__ __launch_bounds__(1024, 4)
void shapelet_fused_kernel(const float* __restrict__ x,
                           const float* __restrict__ s,
                           float* __restrict__ out) {
    __shared__ __align__(16) unsigned short ldsS[K_SH * SSTR];   // 34816 B
    __shared__ __align__(16) unsigned short ldsX[8 * XSTR];      // 69760 B

    const int t    = threadIdx.x;
    const int lane = t & 63;
    const int w    = t >> 6;
    const int r    = lane & 15;
    const int q    = lane >> 4;
    const int c7   = lane & 7;
    const int ub   = (lane >> 3) & 1;
    const int g    = w >> 3;
    const int w7   = w & 7;
    const int mh   = w7 >> 2;
    const int wp   = w7 & 3;
    const int mtb  = 4 * mh;
    const int b    = blockIdx.x;

    {
        const int k = t >> 3, e8 = t & 7;
        const float4* srow = (const float4*)(s + k * L_SH + e8 * 16);
        float4 v[4];
        float sum = 0.0f;
        #pragma unroll
        for (int j = 0; j < 4; ++j) {
            v[j] = srow[j];
            sum += (v[j].x + v[j].y) + (v[j].z + v[j].w);
        }
        sum += __shfl_xor(sum, 1);
        sum += __shfl_xor(sum, 2);
        sum += __shfl_xor(sum, 4);
        const float mean = sum * (1.0f / 128.0f);
        uint4* dst = (uint4*)((char*)ldsS + k * (SSTR * 2) + e8 * 32);
        #pragma unroll
        for (int j = 0; j < 2; ++j) {
            uint4 o;
            o.x = pack2(f2bf(v[2*j].x - mean),   f2bf(v[2*j].y - mean));
            o.y = pack2(f2bf(v[2*j].z - mean),   f2bf(v[2*j].w - mean));
            o.z = pack2(f2bf(v[2*j+1].x - mean), f2bf(v[2*j+1].y - mean));
            o.w = pack2(f2bf(v[2*j+1].z - mean), f2bf(v[2*j+1].w - mean));
            dst[j] = o;
        }
        if (e8 == 7) *(uint4*)((char*)ldsS + k * (SSTR * 2) + 256) = make_uint4(0,0,0,0);
    }
    {
        const float* __restrict__ xb = x + (size_t)b * T_LEN;
        const int a = (t ^ (t >> 3)) & 7;
        for (int i = (t >> 3); i < XSTR / 8; i += 128) {
            const int p0 = 8 * i;
            float xv[16];
            if (p0 + 16 <= T_LEN) {
                const float4* sp = (const float4*)(xb + p0);
                #pragma unroll
                for (int j = 0; j < 4; ++j) *(float4*)(xv + 4 * j) = sp[j];
            } else {
                #pragma unroll
                for (int j = 0; j < 16; ++j) {
                    const int gi = p0 + j;
                    xv[j] = (gi < T_LEN) ? xb[gi] : 0.0f;
                }
            }
            unsigned short bv[16];
            #pragma unroll
            for (int j = 0; j < 16; ++j) bv[j] = f2bf(xv[j]);
            uint4 o;
            o.x = pack2(bv[a],     bv[a + 1]);
            o.y = pack2(bv[a + 2], bv[a + 3]);
            o.z = pack2(bv[a + 4], bv[a + 5]);
            o.w = pack2(bv[a + 6], bv[a + 7]);
            *(uint4*)((char*)ldsX + a * (XSTR * 2) + 2 * p0) = o;
        }
    }
    __syncthreads();

    bf16x8 bfr[2][4];
    #pragma unroll
    for (int kk = 0; kk < 2; ++kk)
        #pragma unroll
        for (int c = 0; c < 4; ++c)
            bfr[kk][c] = __builtin_bit_cast(bf16x8, *(const uint4*)(
                (const char*)ldsS + ((2 * wp + kk) * 16 + r) * (SSTR * 2) + 64 * c + 16 * q));

    h2 rt[5];
    #pragma unroll
    for (int i = 0; i < 5; ++i) rt[i] = __builtin_bit_cast(h2, 0xFC00FC00u);

    const char* xp = (const char*)ldsX + c7 * (XSTR * 2) + 16 * q + 16 * ub + 32 * mtb
                   + g * 256;
    const f32x4 ZCC = (f32x4){0.f, 0.f, 0.f, 0.f};

#define TILE_STEP                                                               \
    {                                                                           \
        bf16x8 afr[10];                                                         \
        _Pragma("unroll")                                                       \
        for (int j = 0; j < 10; ++j)                                            \
            afr[j] = __builtin_bit_cast(bf16x8, *(const uint4*)(xp + 32 * j));  \
        xp += 512;                                                              \
        f32x4 acc0[4], acc1[4];                                                 \
        _Pragma("unroll")                                                       \
        for (int m = 0; m < 4; ++m) {                                           \
            acc0[m] = __builtin_amdgcn_mfma_f32_16x16x32_bf16(afr[m], bfr[0][0], ZCC, 0, 0, 0); \
            acc1[m] = __builtin_amdgcn_mfma_f32_16x16x32_bf16(afr[m], bfr[1][0], ZCC, 0, 0, 0); \
        }                                                                       \
        _Pragma("unroll")                                                       \
        for (int c = 1; c < 4; ++c) {                                           \
            _Pragma("unroll")                                                   \
            for (int m = 0; m < 4; ++m) {                                       \
                acc0[m] = __builtin_amdgcn_mfma_f32_16x16x32_bf16(afr[m + 2*c], bfr[0][c], acc0[m], 0, 0, 0); \
                acc1[m] = __builtin_amdgcn_mfma_f32_16x16x32_bf16(afr[m + 2*c], bfr[1][c], acc1[m], 0, 0, 0); \
            }                                                                   \
        }                                                                       \
        select32(acc0, acc1, rt);                                               \
    }

    for (int st = 0; st < 15; ++st) { TILE_STEP }
    if (g == 0) { TILE_STEP }
#undef TILE_STEP

    if (g == 1 && mh == 0) {
        f32x4 e0 = (f32x4){0.f, 0.f, 0.f, 0.f};
        f32x4 e1 = (f32x4){0.f, 0.f, 0.f, 0.f};
        const char* eb = (const char*)ldsX + c7 * (XSTR * 2) + 7936 + 16 * q + 16 * ub;
        #pragma unroll
        for (int c = 0; c < 4; ++c) {
            const bf16x8 af = __builtin_bit_cast(bf16x8, *(const uint4*)(eb + 64 * c));
            e0 = __builtin_amdgcn_mfma_f32_16x16x32_bf16(af, bfr[0][c], e0, 0, 0, 0);
            e1 = __builtin_amdgcn_mfma_f32_16x16x32_bf16(af, bfr[1][c], e1, 0, 0, 0);
        }
        if (q == 0) insert1_2(cvt2(e0[0], e1[0]), rt);
    }

    #pragma unroll
    for (int mask = 16; mask <= 32; mask <<= 1) {
        h2 sv[5];
        #pragma unroll
        for (int i = 0; i < 5; ++i)
            sv[i] = __builtin_bit_cast(h2, __shfl_xor(__builtin_bit_cast(int, rt[i]), mask));
        merge55_2(rt[0], rt[1], rt[2], rt[3], rt[4], sv[0], sv[1], sv[2], sv[3], sv[4]);
    }

    __syncthreads();
    unsigned int* pbuf = (unsigned int*)ldsS;
    if ((g != 0 || mh != 0) && q == 0) {
        const int reg = (g * 2 + mh) - 1;
        unsigned int* p = pbuf + ((reg * 64) + wp * 16 + r) * 5;
        #pragma unroll
        for (int i = 0; i < 5; ++i) p[i] = __builtin_bit_cast(unsigned int, rt[i]);
    }
    __syncthreads();
    if (g == 0 && mh == 0 && q == 0) {
        #pragma unroll
        for (int reg = 0; reg < 3; ++reg) {
            const unsigned int* p = pbuf + ((reg * 64) + wp * 16 + r) * 5;
            h2 sv[5];
            #pragma unroll
            for (int i = 0; i < 5; ++i) sv[i] = __builtin_bit_cast(h2, p[i]);
            merge55_2(rt[0], rt[1], rt[2], rt[3], rt[4], sv[0], sv[1], sv[2], sv[3], sv[4]);
        }
        const float A0 = (float)rt[0][0], A1 = (float)rt[1][0], A2 = (float)rt[2][0],
                    A3 = (float)rt[3][0], A4 = (float)rt[4][0];
        const float B0 = (float)rt[0][1], B1 = (float)rt[1][1], B2 = (float)rt[2][1],
                    B3 = (float)rt[3][1], B4 = (float)rt[4][1];
        float* ob = out + (size_t)b * (4 * K_SH);
        const int ksA = 32 * wp + r, ksB = ksA + 16;
        const float mA = (((A0 + A1) + (A2 + A3)) + A4) * 0.2f;
        const float mB = (((B0 + B1) + (B2 + B3)) + B4) * 0.2f;
        ob[ksA]           = A0;
        ob[K_SH + ksA]    = mA;
        ob[2*K_SH + ksA]  = A1;
        ob[3*K_SH + ksA]  = fmaxf(A0 - A1, 0.0f);
        ob[ksB]           = B0;
        ob[K_SH + ksB]    = mB;
        ob[2*K_SH + ksB]  = B1;
        ob[3*K_SH + ksB]  = fmaxf(B0 - B1, 0.0f);
    }
}

extern "C" void kernel_launch(void* const* d_in, const int* in_sizes, int n_in,
                              void* d_out, int out_size, void* d_ws, size_t ws_size,
                              hipStream_t stream) {
    const float* x = (const float*)d_in[0];        // (256, 4096) fp32
    const float* s = (const float*)d_in[1];        // (128, 128)  fp32
    float* out = (float*)d_out;                    // (256, 512)  fp32
    const size_t ws_needed = (size_t)B_SZ * 8 * 64 * 5 * sizeof(unsigned int); // 2.5 MB
    if (d_ws != nullptr && ws_size >= ws_needed) {
        unsigned int* wslists = (unsigned int*)d_ws;
        shapelet_oct_kernel<<<8 * B_SZ, 256, 0, stream>>>(x, s, wslists);
        shapelet_merge8_kernel<<<64, 256, 0, stream>>>(wslists, out);
    } else {
        shapelet_fused_kernel<<<B_SZ, 1024, 0, stream>>>(x, s, out);
    }
}

// Round 8
// 98.229 us; speedup vs baseline: 1.5074x; 1.5074x over previous
//
#include <hip/hip_runtime.h>

// Problem constants
#define T_LEN 4096
#define N_WIN 3969          // T - L + 1
#define K_SH  128
#define L_SH  128
#define B_SZ  256

#define SSTR  136           // S row stride (bf16 elems), 272 B
// x copy stride (bf16): 8720 B; stride/4 ≡ 4 (mod 32) -> 8 copy bases on distinct
// banks. Padded so the last tile's reads stay in range.
#define XSTR  4360

typedef __attribute__((ext_vector_type(8))) __bf16 bf16x8;
typedef __attribute__((ext_vector_type(4))) float f32x4;
typedef _Float16 h2 __attribute__((ext_vector_type(2)));   // packed half pair

__device__ __forceinline__ unsigned short f2bf(float f) {
    union { float f; unsigned int u; } c; c.f = f;
    unsigned int u = c.u + 0x7fff + ((c.u >> 16) & 1u);
    return (unsigned short)(u >> 16);
}
__device__ __forceinline__ unsigned int pack2(unsigned short lo, unsigned short hi) {
    return (unsigned int)lo | ((unsigned int)hi << 16);
}

// ---- packed-f16 selection primitives (each op handles BOTH lists) ----
__device__ __forceinline__ h2 max2(h2 a, h2 b) { return __builtin_elementwise_max(a, b); }
__device__ __forceinline__ h2 min2(h2 a, h2 b) { return __builtin_elementwise_min(a, b); }
__device__ __forceinline__ h2 cvt2(float lo, float hi) {   // lo -> elem0, hi -> elem1
    return __builtin_bit_cast(h2, __builtin_amdgcn_cvt_pkrtz(lo, hi));
}
__device__ __forceinline__ void ce2(h2& hi, h2& lo) {
    const h2 m = max2(hi, lo);
    lo = min2(hi, lo);
    hi = m;
}
__device__ __forceinline__ void sort4_2(h2& a, h2& b, h2& c, h2& d) {
    ce2(a, b); ce2(c, d); ce2(a, c); ce2(b, d); ce2(b, c);
}
// top-5 of two descending sorted 4-lists (odd-even merge, 8 comparators)
__device__ __forceinline__ void merge44_top5_2(h2 a0, h2 a1, h2 a2, h2 a3,
                                               h2 b0, h2 b1, h2 b2, h2 b3,
                                               h2& r0, h2& r1, h2& r2, h2& r3, h2& r4) {
    ce2(a0, b0); ce2(a2, b2); ce2(b0, a2);
    ce2(a1, b1); ce2(a3, b3); ce2(b1, a3);
    r0 = a0;
    r1 = a1; r2 = b0; ce2(r1, r2);
    r3 = b1; r4 = a2; ce2(r3, r4);
}
// r = top-5 of union of two descending sorted 5-lists (c_k = max_{i+j=k} min(a_i,b_j))
__device__ __forceinline__ void merge55_2(h2& r0, h2& r1, h2& r2, h2& r3, h2& r4,
                                          h2 s0, h2 s1, h2 s2, h2 s3, h2 s4) {
    const h2 m00 = min2(r0, s0);
    const h2 m10 = min2(r1, s0), m01 = min2(r0, s1);
    const h2 m20 = min2(r2, s0), m11 = min2(r1, s1), m02 = min2(r0, s2);
    const h2 m30 = min2(r3, s0), m21 = min2(r2, s1), m12 = min2(r1, s2), m03 = min2(r0, s3);
    const h2 n0 = max2(r0, s0);
    const h2 n1 = max2(max2(r1, s1), m00);
    const h2 n2 = max2(max2(r2, s2), max2(m10, m01));
    const h2 n3 = max2(max2(max2(r3, s3), m20), max2(m11, m02));
    const h2 n4 = max2(max2(max2(r4, s4), max2(m30, m03)), max2(m21, m12));
    r0 = n0; r1 = n1; r2 = n2; r3 = n3; r4 = n4;
}
// packed single-value insert (epilogue only)
__device__ __forceinline__ void insert1_2(h2 v, h2* rt) {
    h2 b = max2(rt[4], v); h2 m;
    m = max2(rt[3], b);     b     = min2(rt[3], b);     rt[3] = m;
    m = max2(rt[2], rt[3]); rt[3] = min2(rt[2], rt[3]); rt[2] = m;
    m = max2(rt[1], rt[2]); rt[2] = min2(rt[1], rt[2]); rt[1] = m;
    m = max2(rt[0], rt[1]); rt[1] = min2(rt[0], rt[1]); rt[0] = m;
    rt[4] = b;
}
// per-tile: fold 32 acc values (16 per list) into packed running top-5
__device__ __forceinline__ void select32(const f32x4* acc0, const f32x4* acc1, h2* rt) {
    h2 p[16];
    #pragma unroll
    for (int m = 0; m < 4; ++m)
        #pragma unroll
        for (int i = 0; i < 4; ++i)
            p[4 * m + i] = cvt2(acc0[m][i], acc1[m][i]);
    sort4_2(p[0], p[1], p[2],  p[3]);
    sort4_2(p[4], p[5], p[6],  p[7]);
    sort4_2(p[8], p[9], p[10], p[11]);
    sort4_2(p[12], p[13], p[14], p[15]);
    h2 u0, u1, u2, u3, u4, v0, v1, v2, v3, v4;
    merge44_top5_2(p[0], p[1], p[2],  p[3],  p[4],  p[5],  p[6],  p[7],  u0, u1, u2, u3, u4);
    merge44_top5_2(p[8], p[9], p[10], p[11], p[12], p[13], p[14], p[15], v0, v1, v2, v3, v4);
    merge55_2(u0, u1, u2, u3, u4, v0, v1, v2, v3, v4);
    merge55_2(rt[0], rt[1], rt[2], rt[3], rt[4], u0, u1, u2, u3, u4);
}

// Round-8 kernel: grid = B (256 blocks), 512 threads (8 waves, 2/SIMD).
//
// WHY 8 waves: counter reconciliation (R7 post-mortem) shows the kernel is
// LDS-read-throughput bound: with 16 waves, the 4 wp-waves (one per SIMD)
// read IDENTICAL A-fragments (xp is wp-independent) -> 4x duplicated traffic
// on the single per-CU LDS pipe (model: 99% busy; VALU 57%, MFMA 27% both
// reproduced exactly). Here each wave owns 64 shapelets (4 kt16 tiles,
// bfr[4][4] = 64 VGPR) and reuses each afr fragment set for TWO kt-pair
// passes -> duplication 2x, LDS demand halved. VALU becomes the binding
// pipe (~17k cyc/SIMD vs LDS ~15k/CU).
//
// Wave w (0..7): g = w>>2 tile parity, mh = (w>>1)&1 mt-half, wp = w&1
// shapelet half [64*wp, 64*wp+64). launch_bounds(512,2) caps VGPR at 256
// (live peak ~200) -> no spills (R2/R7 failure mode excluded by cap >= need).
__global__ __launch_bounds__(512, 2)
void shapelet_fused8_kernel(const float* __restrict__ x,
                            const float* __restrict__ s,
                            float* __restrict__ out) {
    __shared__ __align__(16) unsigned short ldsS[K_SH * SSTR];   // 34816 B
    __shared__ __align__(16) unsigned short ldsX[8 * XSTR];      // 69760 B

    const int t    = threadIdx.x;
    const int lane = t & 63;
    const int w    = t >> 6;          // 0..7
    const int r    = lane & 15;
    const int q    = lane >> 4;
    const int c7   = lane & 7;
    const int ub   = (lane >> 3) & 1;
    const int g    = w >> 2;          // tile-parity group
    const int mh   = (w >> 1) & 1;    // mt-half
    const int wp   = w & 1;           // shapelet half (64 each)
    const int mtb  = 4 * mh;
    const int b    = blockIdx.x;

    // ---- stage centered S as bf16: 4 threads per row k, 32 elems each ----
    {
        const int k = t >> 2, e4 = t & 3;
        const float4* srow = (const float4*)(s + k * L_SH + e4 * 32);
        float4 v[8];
        float sum = 0.0f;
        #pragma unroll
        for (int j = 0; j < 8; ++j) {
            v[j] = srow[j];
            sum += (v[j].x + v[j].y) + (v[j].z + v[j].w);
        }
        sum += __shfl_xor(sum, 1);
        sum += __shfl_xor(sum, 2);
        const float mean = sum * (1.0f / 128.0f);
        uint4* dst = (uint4*)((char*)ldsS + k * (SSTR * 2) + e4 * 64);
        #pragma unroll
        for (int j = 0; j < 4; ++j) {
            uint4 o;
            o.x = pack2(f2bf(v[2*j].x - mean),   f2bf(v[2*j].y - mean));
            o.y = pack2(f2bf(v[2*j].z - mean),   f2bf(v[2*j].w - mean));
            o.z = pack2(f2bf(v[2*j+1].x - mean), f2bf(v[2*j+1].y - mean));
            o.w = pack2(f2bf(v[2*j+1].z - mean), f2bf(v[2*j+1].w - mean));
            dst[j] = o;
        }
        if (e4 == 3) *(uint4*)((char*)ldsS + k * (SSTR * 2) + 256) = make_uint4(0,0,0,0);
    }

    // ---- stage x row as 8 shifted bf16 copies (512 threads: 9 iters) ----
    {
        const float* __restrict__ xb = x + (size_t)b * T_LEN;
        const int a = (t ^ (t >> 3)) & 7;   // bijective per 8-thread chunk group
        for (int i = (t >> 3); i < XSTR / 8; i += 64) {
            const int p0 = 8 * i;
            float xv[16];
            if (p0 + 16 <= T_LEN) {
                const float4* sp = (const float4*)(xb + p0);
                #pragma unroll
                for (int j = 0; j < 4; ++j) *(float4*)(xv + 4 * j) = sp[j];
            } else {
                #pragma unroll
                for (int j = 0; j < 16; ++j) {
                    const int gi = p0 + j;
                    xv[j] = (gi < T_LEN) ? xb[gi] : 0.0f;
                }
            }
            unsigned short bv[16];
            #pragma unroll
            for (int j = 0; j < 16; ++j) bv[j] = f2bf(xv[j]);
            uint4 o;
            o.x = pack2(bv[a],     bv[a + 1]);
            o.y = pack2(bv[a + 2], bv[a + 3]);
            o.z = pack2(bv[a + 4], bv[a + 5]);
            o.w = pack2(bv[a + 6], bv[a + 7]);
            *(uint4*)((char*)ldsX + a * (XSTR * 2) + 2 * p0) = o;
        }
    }
    __syncthreads();

    // ---- hoist B fragments: 4 kt16 tiles (64 shapelets) x 4 K-chunks ----
    bf16x8 bfr[4][4];
    #pragma unroll
    for (int kt = 0; kt < 4; ++kt)
        #pragma unroll
        for (int c = 0; c < 4; ++c)
            bfr[kt][c] = __builtin_bit_cast(bf16x8, *(const uint4*)(
                (const char*)ldsS + ((64 * wp + 16 * kt + r)) * (SSTR * 2) + 64 * c + 16 * q));

    // two packed running top-5 sets:
    // rtP: elem0 -> ks = 64wp +      r, elem1 -> ks = 64wp + 16 + r  (kt 0,1)
    // rtQ: elem0 -> ks = 64wp + 32 + r, elem1 -> ks = 64wp + 48 + r  (kt 2,3)
    h2 rtP[5], rtQ[5];
    #pragma unroll
    for (int i = 0; i < 5; ++i) {
        rtP[i] = __builtin_bit_cast(h2, 0xFC00FC00u);
        rtQ[i] = __builtin_bit_cast(h2, 0xFC00FC00u);
    }

    // group g starts at tile g; advances by 2 tiles (512 B) per step
    const char* xp = (const char*)ldsX + c7 * (XSTR * 2) + 16 * q + 16 * ub + 32 * mtb
                   + g * 256;

    const f32x4 ZCC = (f32x4){0.f, 0.f, 0.f, 0.f};

    // Per step: ONE afr load set feeds TWO kt-pair MFMA passes (the LDS win).
#define TILE_STEP                                                               \
    {                                                                           \
        bf16x8 afr[10];                                                         \
        _Pragma("unroll")                                                       \
        for (int j = 0; j < 10; ++j)                                            \
            afr[j] = __builtin_bit_cast(bf16x8, *(const uint4*)(xp + 32 * j));  \
        xp += 512;                                                              \
        f32x4 acc0[4], acc1[4];                                                 \
        _Pragma("unroll")                                                       \
        for (int m = 0; m < 4; ++m) {                                           \
            acc0[m] = __builtin_amdgcn_mfma_f32_16x16x32_bf16(afr[m], bfr[0][0], ZCC, 0, 0, 0); \
            acc1[m] = __builtin_amdgcn_mfma_f32_16x16x32_bf16(afr[m], bfr[1][0], ZCC, 0, 0, 0); \
        }                                                                       \
        _Pragma("unroll")                                                       \
        for (int c = 1; c < 4; ++c) {                                           \
            _Pragma("unroll")                                                   \
            for (int m = 0; m < 4; ++m) {                                       \
                acc0[m] = __builtin_amdgcn_mfma_f32_16x16x32_bf16(afr[m + 2*c], bfr[0][c], acc0[m], 0, 0, 0); \
                acc1[m] = __builtin_amdgcn_mfma_f32_16x16x32_bf16(afr[m + 2*c], bfr[1][c], acc1[m], 0, 0, 0); \
            }                                                                   \
        }                                                                       \
        select32(acc0, acc1, rtP);                                              \
        _Pragma("unroll")                                                       \
        for (int m = 0; m < 4; ++m) {                                           \
            acc0[m] = __builtin_amdgcn_mfma_f32_16x16x32_bf16(afr[m], bfr[2][0], ZCC, 0, 0, 0); \
            acc1[m] = __builtin_amdgcn_mfma_f32_16x16x32_bf16(afr[m], bfr[3][0], ZCC, 0, 0, 0); \
        }                                                                       \
        _Pragma("unroll")                                                       \
        for (int c = 1; c < 4; ++c) {                                           \
            _Pragma("unroll")                                                   \
            for (int m = 0; m < 4; ++m) {                                       \
                acc0[m] = __builtin_amdgcn_mfma_f32_16x16x32_bf16(afr[m + 2*c], bfr[2][c], acc0[m], 0, 0, 0); \
                acc1[m] = __builtin_amdgcn_mfma_f32_16x16x32_bf16(afr[m + 2*c], bfr[3][c], acc1[m], 0, 0, 0); \
            }                                                                   \
        }                                                                       \
        select32(acc0, acc1, rtQ);                                              \
    }

    // g=0: tiles 0,2,...,30 (16 steps); g=1: tiles 1,3,...,29 (15 steps)
    const int nst = (g == 0) ? 16 : 15;
    for (int st = 0; st < nst; ++st) { TILE_STEP }
#undef TILE_STEP

    // ---- boundary row n = 3968 -> (g=1, mh=0) waves, both wp halves ----
    if (g == 1 && mh == 0) {
        f32x4 e[4];
        #pragma unroll
        for (int kt = 0; kt < 4; ++kt) e[kt] = (f32x4){0.f, 0.f, 0.f, 0.f};
        const char* eb = (const char*)ldsX + c7 * (XSTR * 2) + 7936 + 16 * q + 16 * ub;
        #pragma unroll
        for (int c = 0; c < 4; ++c) {
            const bf16x8 af = __builtin_bit_cast(bf16x8, *(const uint4*)(eb + 64 * c));
            #pragma unroll
            for (int kt = 0; kt < 4; ++kt)
                e[kt] = __builtin_amdgcn_mfma_f32_16x16x32_bf16(af, bfr[kt][c], e[kt], 0, 0, 0);
        }
        if (q == 0) {
            insert1_2(cvt2(e[0][0], e[1][0]), rtP);
            insert1_2(cvt2(e[2][0], e[3][0]), rtQ);
        }
    }

    // ---- butterfly merge across quads for both sets ----
    #pragma unroll
    for (int mask = 16; mask <= 32; mask <<= 1) {
        h2 sv[5], sw[5];
        #pragma unroll
        for (int i = 0; i < 5; ++i) {
            sv[i] = __builtin_bit_cast(h2, __shfl_xor(__builtin_bit_cast(int, rtP[i]), mask));
            sw[i] = __builtin_bit_cast(h2, __shfl_xor(__builtin_bit_cast(int, rtQ[i]), mask));
        }
        merge55_2(rtP[0], rtP[1], rtP[2], rtP[3], rtP[4], sv[0], sv[1], sv[2], sv[3], sv[4]);
        merge55_2(rtQ[0], rtQ[1], rtQ[2], rtQ[3], rtQ[4], sw[0], sw[1], sw[2], sw[3], sw[4]);
    }

    // ---- cross-(g, mh) merge via LDS; per wp: 3 writers, reader (g=0,mh=0) ----
    __syncthreads();   // ldsS reads (bfr hoist) long done; reuse as scratch
    unsigned int* pbuf = (unsigned int*)ldsS;   // [(wp*3 + region)*16 + r][10]
    const int gm = g * 2 + mh;                  // 0..3 window-group
    if (gm != 0 && q == 0) {
        unsigned int* p = pbuf + ((wp * 3 + (gm - 1)) * 16 + r) * 10;
        #pragma unroll
        for (int i = 0; i < 5; ++i) {
            p[i]     = __builtin_bit_cast(unsigned int, rtP[i]);
            p[5 + i] = __builtin_bit_cast(unsigned int, rtQ[i]);
        }
    }
    __syncthreads();
    if (gm == 0 && q == 0) {
        #pragma unroll
        for (int reg = 0; reg < 3; ++reg) {
            const unsigned int* p = pbuf + ((wp * 3 + reg) * 16 + r) * 10;
            h2 sv[5], sw[5];
            #pragma unroll
            for (int i = 0; i < 5; ++i) {
                sv[i] = __builtin_bit_cast(h2, p[i]);
                sw[i] = __builtin_bit_cast(h2, p[5 + i]);
            }
            merge55_2(rtP[0], rtP[1], rtP[2], rtP[3], rtP[4], sv[0], sv[1], sv[2], sv[3], sv[4]);
            merge55_2(rtQ[0], rtQ[1], rtQ[2], rtQ[3], rtQ[4], sw[0], sw[1], sw[2], sw[3], sw[4]);
        }

        // emit features for 4 lists: ks = 64wp + {0,16,32,48} + r
        float* ob = out + (size_t)b * (4 * K_SH);
        const h2* rts[2] = { rtP, rtQ };
        #pragma unroll
        for (int setI = 0; setI < 2; ++setI) {
            const h2* rt = rts[setI];
            const float A0 = (float)rt[0][0], A1 = (float)rt[1][0], A2 = (float)rt[2][0],
                        A3 = (float)rt[3][0], A4 = (float)rt[4][0];
            const float B0 = (float)rt[0][1], B1 = (float)rt[1][1], B2 = (float)rt[2][1],
                        B3 = (float)rt[3][1], B4 = (float)rt[4][1];
            const int ksA = 64 * wp + 32 * setI + r, ksB = ksA + 16;
            const float mA = (((A0 + A1) + (A2 + A3)) + A4) * 0.2f;
            const float mB = (((B0 + B1) + (B2 + B3)) + B4) * 0.2f;
            ob[ksA]           = A0;
            ob[K_SH + ksA]    = mA;
            ob[2*K_SH + ksA]  = A1;
            ob[3*K_SH + ksA]  = fmaxf(A0 - A1, 0.0f);
            ob[ksB]           = B0;
            ob[K_SH + ksB]    = mB;
            ob[2*K_SH + ksB]  = B1;
            ob[3*K_SH + ksB]  = fmaxf(B0 - B1, 0.0f);
        }
    }
}

extern "C" void kernel_launch(void* const* d_in, const int* in_sizes, int n_in,
                              void* d_out, int out_size, void* d_ws, size_t ws_size,
                              hipStream_t stream) {
    const float* x = (const float*)d_in[0];        // (256, 4096) fp32
    const float* s = (const float*)d_in[1];        // (128, 128)  fp32
    float* out = (float*)d_out;                    // (256, 512)  fp32
    shapelet_fused8_kernel<<<B_SZ, 512, 0, stream>>>(x, s, out);
}